// Round 4
// baseline (525.075 us; speedup 1.0000x reference)
//
#include <hip/hip_runtime.h>
#include <stdint.h>

// B=8, S=1024, D_MODEL=256, dk=dv=16, 128 pseudo-heads of 1024x16.
// ws layout (floats): Q[2M] | K[2M] | V[2M] | AO[2M] -> 32 MB.

typedef _Float16 f16x8 __attribute__((ext_vector_type(8)));
typedef _Float16 f16x4 __attribute__((ext_vector_type(4)));
typedef float    f32x4 __attribute__((ext_vector_type(4)));

// ---------------------------------------------------------------------------
// fp32 GEMM: C[8192 x 256] = A[8192 x 256] @ W[256 x 256] + bias[256]
// 64x64 tile, BK=32 (8 k-iters, 2 barriers each), 4x4 acc per thread.
// ---------------------------------------------------------------------------
__global__ __launch_bounds__(256) void gemm256(
    const float* __restrict__ A, const float* __restrict__ W,
    const float* __restrict__ bias, float* __restrict__ C)
{
    __shared__ float As[64][36];
    __shared__ float Bs[32][68];
    const int tid = threadIdx.x;
    const int tx = tid & 15, ty = tid >> 4;
    const int m0 = blockIdx.x << 6, n0 = blockIdx.y << 6;
    const int ar = tid >> 3, ac = (tid & 7) << 2;   // 32 rows x 32 cols, x2
    const int br = tid >> 4, bc = (tid & 15) << 2;  // 16 rows x 64 cols, x2

    float acc[4][4] = {};

    for (int k0 = 0; k0 < 256; k0 += 32) {
        float4 a0 = *(const float4*)(A + (size_t)(m0 + ar) * 256 + k0 + ac);
        float4 a1 = *(const float4*)(A + (size_t)(m0 + ar + 32) * 256 + k0 + ac);
        float4 b0 = *(const float4*)(W + (size_t)(k0 + br) * 256 + n0 + bc);
        float4 b1 = *(const float4*)(W + (size_t)(k0 + br + 16) * 256 + n0 + bc);
        *(float4*)&As[ar][ac]      = a0;
        *(float4*)&As[ar + 32][ac] = a1;
        *(float4*)&Bs[br][bc]      = b0;
        *(float4*)&Bs[br + 16][bc] = b1;
        __syncthreads();
        #pragma unroll
        for (int kk = 0; kk < 32; ++kk) {
            float av[4];
            #pragma unroll
            for (int i = 0; i < 4; ++i) av[i] = As[(ty << 2) + i][kk];
            float4 bv = *(float4*)&Bs[kk][tx << 2];
            #pragma unroll
            for (int i = 0; i < 4; ++i) {
                acc[i][0] += av[i] * bv.x;
                acc[i][1] += av[i] * bv.y;
                acc[i][2] += av[i] * bv.z;
                acc[i][3] += av[i] * bv.w;
            }
        }
        __syncthreads();
    }

    float4 bb = *(const float4*)(bias + n0 + (tx << 2));
    #pragma unroll
    for (int i = 0; i < 4; ++i) {
        float4 o = make_float4(acc[i][0] + bb.x, acc[i][1] + bb.y,
                               acc[i][2] + bb.z, acc[i][3] + bb.w);
        *(float4*)(C + (size_t)(m0 + (ty << 2) + i) * 256 + n0 + (tx << 2)) = o;
    }
}

// ---------------------------------------------------------------------------
// Attention
// ---------------------------------------------------------------------------
// order-preserving uint -> float (monotone bijection on float bit patterns)
__device__ __forceinline__ float u2f(unsigned int m) {
    unsigned int x = (m & 0x80000000u) ? (m ^ 0x80000000u) : ~m;
    return __uint_as_float(x);
}

__device__ __forceinline__ float dot16(const float4& q0, const float4& q1,
                                       const float4& q2, const float4& q3,
                                       const float* kf) {
    return q0.x*kf[0] + q0.y*kf[1] + q0.z*kf[2]  + q0.w*kf[3]
         + q1.x*kf[4] + q1.y*kf[5] + q1.z*kf[6]  + q1.w*kf[7]
         + q2.x*kf[8] + q2.y*kf[9] + q2.z*kf[10] + q2.w*kf[11]
         + q3.x*kf[12]+ q3.y*kf[13]+ q3.z*kf[14] + q3.w*kf[15];
}

// grid 512 = 128 heads x 4 row-groups; block 512 (8 waves).
// LDS: union{Ssc f32[8][1024]; P f16[16][1032]} 33KB + Vt f16[16][1032] 33KB
//      + part 4KB + sums[2][8]. ~70 KB -> 2 blocks/CU.
// Rows 1032 (pad +8 f16 = 4 dwords): MFMA frag reads go 16-way -> 2-way (free).
__global__ __attribute__((amdgpu_waves_per_eu(4, 4)))
__launch_bounds__(512) void attn(
    const float* __restrict__ Qb, const float* __restrict__ Kb,
    const float* __restrict__ Vb, float* __restrict__ Ob)
{
    __shared__ union {
        float    Ssc[8][1024];
        _Float16 P[16][1032];
    } U;
    __shared__ _Float16 Vt[16][1032];   // V transposed f16: Vt[d][k]
    __shared__ float part[1024];        // [8 waves][8 rows][16 d]
    __shared__ float sums[2][8];        // double-buffered row sums

    const int tid  = threadIdx.x;
    const int wave = tid >> 6, lane = tid & 63;
    const int head = blockIdx.x >> 2, grp = blockIdx.x & 3;
    const float* Qh = Qb + ((size_t)head << 14);
    const float* Kh = Kb + ((size_t)head << 14);
    const float* Vh = Vb + ((size_t)head << 14);

    // ---- stage V transposed into LDS as f16 (one-time) ----
    for (int i = tid; i < 4096; i += 512) {
        float4 v = ((const float4*)Vh)[i];
        const int k = i >> 2, d0 = (i & 3) << 2;
        Vt[d0 + 0][k] = (_Float16)v.x;
        Vt[d0 + 1][k] = (_Float16)v.y;
        Vt[d0 + 2][k] = (_Float16)v.z;
        Vt[d0 + 3][k] = (_Float16)v.w;
    }

    // ---- K fragments (fp32 registers): columns c0, c1 ----
    const int c0 = (wave << 7) + lane;
    const int c1 = c0 + 64;
    float Kf0[16], Kf1[16];
    {
        const float4* kp = (const float4*)(Kh + ((size_t)c0 << 4));
        float4 a = kp[0], b = kp[1], c = kp[2], d = kp[3];
        Kf0[0]=a.x; Kf0[1]=a.y; Kf0[2]=a.z;  Kf0[3]=a.w;
        Kf0[4]=b.x; Kf0[5]=b.y; Kf0[6]=b.z;  Kf0[7]=b.w;
        Kf0[8]=c.x; Kf0[9]=c.y; Kf0[10]=c.z; Kf0[11]=c.w;
        Kf0[12]=d.x;Kf0[13]=d.y;Kf0[14]=d.z; Kf0[15]=d.w;
        kp = (const float4*)(Kh + ((size_t)c1 << 4));
        a = kp[0]; b = kp[1]; c = kp[2]; d = kp[3];
        Kf1[0]=a.x; Kf1[1]=a.y; Kf1[2]=a.z;  Kf1[3]=a.w;
        Kf1[4]=b.x; Kf1[5]=b.y; Kf1[6]=b.z;  Kf1[7]=b.w;
        Kf1[8]=c.x; Kf1[9]=c.y; Kf1[10]=c.z; Kf1[11]=c.w;
        Kf1[12]=d.x;Kf1[13]=d.y;Kf1[14]=d.z; Kf1[15]=d.w;
    }
    __syncthreads();

    for (int chunk = 0; chunk < 32; ++chunk) {
        const int qbase = (grp << 8) + (chunk << 3);
        const int sb = chunk & 1;

        // ---- phase 1: scores (x 1/8) into Ssc ----
        #pragma unroll
        for (int r = 0; r < 8; ++r) {
            const float4* qp = (const float4*)(Qh + ((size_t)(qbase + r) << 4));
            float4 q0 = qp[0], q1 = qp[1], q2 = qp[2], q3 = qp[3];
            U.Ssc[r][c0] = dot16(q0, q1, q2, q3, Kf0) * 0.125f;
            U.Ssc[r][c1] = dot16(q0, q1, q2, q3, Kf1) * 0.125f;
        }
        __syncthreads();   // B1: scores visible

        // ---- wave w owns row w. Lane owns 4 groups of 4 CONTIGUOUS columns
        //      (median/exp/sum are permutation-invariant) -> 4x ds_read_b128.
        float s[16];
        #pragma unroll
        for (int b = 0; b < 4; ++b) {
            f32x4 v = *(const f32x4*)&U.Ssc[wave][(b << 8) + (lane << 2)];
            s[(b << 2) + 0] = v.x; s[(b << 2) + 1] = v.y;
            s[(b << 2) + 2] = v.z; s[(b << 2) + 3] = v.w;
        }
        __syncthreads();   // B2: Ssc consumed -> reusable as P

        // ---- phase 2: exact lower median; quaternary bisection, early exit ----
        // invariant: count(<= vLo) = cl < 512 <= ch = count(<= u2f(hi))
        unsigned int lo = 0x00800000u, hi = 0xFF7FFFFFu;
        int cl = 0, ch = 1024;
        float vLo = __uint_as_float(0xFF800000u);   // -inf
        while (lo < hi && (ch - cl) != 1) {
            unsigned int span = hi - lo;
            if (span >= 4) {
                unsigned int m1 = lo + (span >> 2);
                unsigned int m2 = lo + (span >> 1);
                unsigned int m3 = lo + span - (span >> 2);
                float t1 = u2f(m1), t2 = u2f(m2), t3 = u2f(m3);
                int n1 = 0, n2 = 0, n3 = 0;
                #pragma unroll
                for (int j = 0; j < 16; ++j) {
                    n1 += __popcll(__ballot(s[j] <= t1));
                    n2 += __popcll(__ballot(s[j] <= t2));
                    n3 += __popcll(__ballot(s[j] <= t3));
                }
                if (n1 >= 512)      { hi = m1; ch = n1; }
                else if (n2 >= 512) { lo = m1 + 1; cl = n1; vLo = t1; hi = m2; ch = n2; }
                else if (n3 >= 512) { lo = m2 + 1; cl = n2; vLo = t2; hi = m3; ch = n3; }
                else                { lo = m3 + 1; cl = n3; vLo = t3; }
            } else {
                unsigned int m2 = lo + (span >> 1);
                float t2 = u2f(m2);
                int n2 = 0;
                #pragma unroll
                for (int j = 0; j < 16; ++j)
                    n2 += __popcll(__ballot(s[j] <= t2));
                if (n2 >= 512) { hi = m2; ch = n2; }
                else           { lo = m2 + 1; cl = n2; vLo = t2; }
            }
        }
        float medf;
        if (ch - cl == 1) {
            // exactly one element in (vLo, u2f(hi)]; cl==511 -> it is the median
            float cand = 3.4e38f;
            #pragma unroll
            for (int j = 0; j < 16; ++j)
                cand = fminf(cand, (s[j] > vLo) ? s[j] : 3.4e38f);
            #pragma unroll
            for (int off = 32; off > 0; off >>= 1)
                cand = fminf(cand, __shfl_xor(cand, off));
            medf = cand;
        } else {
            medf = u2f(lo);
        }

        // ---- phase 2.5: masked exp (|s|<4: no max-shift needed), f16 round,
        //      row-sum of rounded values, vectorized P writes ----
        float sum = 0.f;
        #pragma unroll
        for (int b = 0; b < 4; ++b) {
            f16x4 hv;
            #pragma unroll
            for (int jj = 0; jj < 4; ++jj) {
                float e = (s[(b << 2) + jj] > medf) ? __expf(s[(b << 2) + jj]) : 0.f;
                _Float16 h = (_Float16)e;
                hv[jj] = h;
                sum += (float)h;
            }
            *(f16x4*)&U.P[wave][(b << 8) + (lane << 2)] = hv;
        }
        #pragma unroll
        for (int off = 32; off > 0; off >>= 1) sum += __shfl_xor(sum, off);
        if (lane == 0) sums[sb][wave] = sum;
        __syncthreads();   // B3: P + sums visible

        // ---- phase 3: PV via MFMA, K split 8 ways across waves ----
        f32x4 acc = {0.f, 0.f, 0.f, 0.f};
        const int fm = lane & 15, fq = lane >> 4;
        const _Float16* Pr = &U.P[fm][fq << 3];
        const _Float16* Vr = &Vt[fm][fq << 3];
        #pragma unroll
        for (int kb = 0; kb < 4; ++kb) {
            const int ko = ((wave << 2) + kb) << 5;
            f16x8 a = *(const f16x8*)(Pr + ko);
            f16x8 b = *(const f16x8*)(Vr + ko);
            acc = __builtin_amdgcn_mfma_f32_16x16x32_f16(a, b, acc, 0, 0, 0);
        }
        if (lane < 32) {   // C rows 0-7 live in quads 0-1
            #pragma unroll
            for (int i = 0; i < 4; ++i)
                part[(wave << 7) + (((fq << 2) + i) << 4) + fm] = acc[i];
        }
        __syncthreads();   // B4: partials visible (also: P reads done)

        // ---- reduce 8 partials + store. Rotate the 2 active waves by chunk.
        // No trailing barrier: next phase-1 writes Ssc (not part/sums[sb]),
        // and chunk c+1's part writes come 2 barriers later.
        const int rw = (wave - chunk) & 7;
        if (rw < 2) {
            const int t2 = (rw << 6) + lane;       // 0..127
            const int r = t2 >> 4, d = t2 & 15;
            float o = 0.f;
            #pragma unroll
            for (int w = 0; w < 8; ++w) o += part[(w << 7) + t2];
            const float inv = 1.0f / sums[sb][r];
            const int q = qbase + r;
            const int h = head >> 3, bp = head & 7;
            float* dst = Ob + (((size_t)(h >> 1)) << 18)
                            + ((size_t)(((h & 1) << 9) + (q >> 1)) << 8)
                            + ((q & 1) << 7) + (bp << 4) + d;
            *dst = o * inv;
        }
    }
}

// ---------------------------------------------------------------------------
extern "C" void kernel_launch(void* const* d_in, const int* in_sizes, int n_in,
                              void* d_out, int out_size, void* d_ws, size_t ws_size,
                              hipStream_t stream) {
    const float* x  = (const float*)d_in[0];
    const float* y  = (const float*)d_in[1];
    const float* Wq = (const float*)d_in[2];
    const float* bq = (const float*)d_in[3];
    const float* Wk = (const float*)d_in[4];
    const float* bk = (const float*)d_in[5];
    const float* Wv = (const float*)d_in[6];
    const float* bv = (const float*)d_in[7];
    const float* Wo = (const float*)d_in[8];
    const float* bo = (const float*)d_in[9];
    float* out = (float*)d_out;

    float* Q  = (float*)d_ws;
    float* K  = Q + 2097152;
    float* V  = K + 2097152;
    float* AO = V + 2097152;

    dim3 g(128, 4), b(256);
    gemm256<<<g, b, 0, stream>>>(x, Wq, bq, Q);
    gemm256<<<g, b, 0, stream>>>(y, Wk, bk, K);
    gemm256<<<g, b, 0, stream>>>(y, Wv, bv, V);
    attn<<<dim3(512), dim3(512), 0, stream>>>(Q, K, V, AO);
    gemm256<<<g, b, 0, stream>>>(AO, Wo, bo, out);
}

// Round 5
// 373.256 us; speedup vs baseline: 1.4067x; 1.4067x over previous
//
#include <hip/hip_runtime.h>
#include <stdint.h>

// B=8, S=1024, D_MODEL=256, dk=dv=16, 128 pseudo-heads of 1024x16.
// ws layout (floats): Q[2M] | K[2M] | V[2M] | AO[2M] -> 32 MB.

typedef _Float16 f16x8 __attribute__((ext_vector_type(8)));
typedef _Float16 f16x4 __attribute__((ext_vector_type(4)));
typedef float    f32x4 __attribute__((ext_vector_type(4)));

// ---------------------------------------------------------------------------
// fp32 GEMM core: C[8192 x 256] = A @ W + bias. 64x64 tile, BK=32, 256 thr.
// Thread (tx,ty) owns rows {ty+16i}, cols {4tx..4tx+3}. As stride 36 dw:
// row-read bank group = 4*ty mod 32 -> 2-way (free), float4-aligned.
// ---------------------------------------------------------------------------
__device__ __forceinline__ void gemm_core(const float* __restrict__ A,
                                          const float* __restrict__ W,
                                          const float* __restrict__ bias,
                                          float* __restrict__ C)
{
    __shared__ float As[64][36];
    __shared__ float Bs[32][68];
    const int tid = threadIdx.x;
    const int tx = tid & 15, ty = tid >> 4;
    const int m0 = blockIdx.x << 6, n0 = blockIdx.y << 6;
    const int ar = tid >> 3, ac = (tid & 7) << 2;   // 32 rows x 32 cols, x2
    const int br = tid >> 4, bc = (tid & 15) << 2;  // 16 rows x 64 cols, x2

    float acc[4][4] = {};

    for (int k0 = 0; k0 < 256; k0 += 32) {
        float4 a0 = *(const float4*)(A + (size_t)(m0 + ar) * 256 + k0 + ac);
        float4 a1 = *(const float4*)(A + (size_t)(m0 + ar + 32) * 256 + k0 + ac);
        float4 b0 = *(const float4*)(W + (size_t)(k0 + br) * 256 + n0 + bc);
        float4 b1 = *(const float4*)(W + (size_t)(k0 + br + 16) * 256 + n0 + bc);
        *(float4*)&As[ar][ac]      = a0;
        *(float4*)&As[ar + 32][ac] = a1;
        *(float4*)&Bs[br][bc]      = b0;
        *(float4*)&Bs[br + 16][bc] = b1;
        __syncthreads();
        #pragma unroll
        for (int kk = 0; kk < 32; kk += 4) {
            float4 av[4], bv[4];
            #pragma unroll
            for (int i = 0; i < 4; ++i)
                av[i] = *(float4*)&As[ty + (i << 4)][kk];
            #pragma unroll
            for (int k2 = 0; k2 < 4; ++k2)
                bv[k2] = *(float4*)&Bs[kk + k2][tx << 2];
            #pragma unroll
            for (int i = 0; i < 4; ++i) {
                const float* ap = (const float*)&av[i];
                #pragma unroll
                for (int k2 = 0; k2 < 4; ++k2) {
                    const float* bp = (const float*)&bv[k2];
                    const float a = ap[k2];
                    acc[i][0] += a * bp[0];
                    acc[i][1] += a * bp[1];
                    acc[i][2] += a * bp[2];
                    acc[i][3] += a * bp[3];
                }
            }
        }
        __syncthreads();
    }

    float4 bb = *(const float4*)(bias + n0 + (tx << 2));
    #pragma unroll
    for (int i = 0; i < 4; ++i) {
        float4 o = make_float4(acc[i][0] + bb.x, acc[i][1] + bb.y,
                               acc[i][2] + bb.z, acc[i][3] + bb.w);
        *(float4*)(C + (size_t)(m0 + ty + (i << 4)) * 256 + n0 + (tx << 2)) = o;
    }
}

// Fused Q/K/V projection: grid (128, 4, 3), z selects which GEMM.
__global__ __launch_bounds__(256) void gemmQKV(
    const float* __restrict__ x, const float* __restrict__ y,
    const float* __restrict__ Wq, const float* __restrict__ bq,
    const float* __restrict__ Wk, const float* __restrict__ bk,
    const float* __restrict__ Wv, const float* __restrict__ bv,
    float* __restrict__ Q, float* __restrict__ K, float* __restrict__ V)
{
    const int z = blockIdx.z;
    const float* A = (z == 0) ? x  : y;
    const float* W = (z == 0) ? Wq : (z == 1) ? Wk : Wv;
    const float* b = (z == 0) ? bq : (z == 1) ? bk : bv;
    float*       C = (z == 0) ? Q  : (z == 1) ? K  : V;
    gemm_core(A, W, b, C);
}

__global__ __launch_bounds__(256) void gemmOut(
    const float* __restrict__ A, const float* __restrict__ W,
    const float* __restrict__ b, float* __restrict__ C)
{
    gemm_core(A, W, b, C);
}

// ---------------------------------------------------------------------------
// Attention
// ---------------------------------------------------------------------------
// order-preserving code <-> float (monotone bijection on float bit patterns)
__device__ __forceinline__ float u2f(unsigned int m) {
    unsigned int x = (m & 0x80000000u) ? (m ^ 0x80000000u) : ~m;
    return __uint_as_float(x);
}
__device__ __forceinline__ unsigned int f2u(float f) {
    unsigned int x = __float_as_uint(f);
    return (x & 0x80000000u) ? ~x : (x | 0x80000000u);
}

__device__ __forceinline__ float dot16(const float4& q0, const float4& q1,
                                       const float4& q2, const float4& q3,
                                       const float* kf) {
    return q0.x*kf[0] + q0.y*kf[1] + q0.z*kf[2]  + q0.w*kf[3]
         + q1.x*kf[4] + q1.y*kf[5] + q1.z*kf[6]  + q1.w*kf[7]
         + q2.x*kf[8] + q2.y*kf[9] + q2.z*kf[10] + q2.w*kf[11]
         + q3.x*kf[12]+ q3.y*kf[13]+ q3.z*kf[14] + q3.w*kf[15];
}

// grid (128 heads, 6 groups) = 768 blocks = exactly 3/CU at waves_per_eu(6,6).
// LDS: union{Ssc f32[8][1024]; P f16[16][1032]; Vt staging} 33KB + part 4KB
//      + sums -> 37.2 KB. V fragments live in REGISTERS after one staging pass.
__global__ __attribute__((amdgpu_waves_per_eu(6, 6)))
__launch_bounds__(512) void attn(
    const float* __restrict__ Qb, const float* __restrict__ Kb,
    const float* __restrict__ Vb, float* __restrict__ Ob)
{
    __shared__ union {
        float    Ssc[8][1024];
        _Float16 P[16][1032];
        _Float16 Vt[16][1032];
    } U;
    __shared__ float part[1024];   // [8 waves][8 rows][16 d]
    __shared__ float sums[2][8];   // double-buffered row sums

    const int tid  = threadIdx.x;
    const int wave = tid >> 6, lane = tid & 63;
    const int head = blockIdx.x, grp = blockIdx.y;
    const float* Qh = Qb + ((size_t)head << 14);
    const float* Kh = Kb + ((size_t)head << 14);
    const float* Vh = Vb + ((size_t)head << 14);
    const int fm = lane & 15, fq = lane >> 4;

    // ---- stage V transposed (f16) into the union, grab register fragments ----
    for (int i = tid; i < 4096; i += 512) {
        float4 v = ((const float4*)Vh)[i];
        const int k = i >> 2, d0 = (i & 3) << 2;
        U.Vt[d0 + 0][k] = (_Float16)v.x;
        U.Vt[d0 + 1][k] = (_Float16)v.y;
        U.Vt[d0 + 2][k] = (_Float16)v.z;
        U.Vt[d0 + 3][k] = (_Float16)v.w;
    }
    __syncthreads();               // staging complete
    f16x8 Vf[4];
    #pragma unroll
    for (int kb = 0; kb < 4; ++kb)
        Vf[kb] = *(const f16x8*)&U.Vt[fm][(((wave << 2) + kb) << 5) + (fq << 3)];

    // ---- K fragments (fp32 registers): columns c0, c1 ----
    const int c0 = (wave << 7) + lane;
    const int c1 = c0 + 64;
    float Kf0[16], Kf1[16];
    {
        const float4* kp = (const float4*)(Kh + ((size_t)c0 << 4));
        float4 a = kp[0], b = kp[1], c = kp[2], d = kp[3];
        Kf0[0]=a.x; Kf0[1]=a.y; Kf0[2]=a.z;  Kf0[3]=a.w;
        Kf0[4]=b.x; Kf0[5]=b.y; Kf0[6]=b.z;  Kf0[7]=b.w;
        Kf0[8]=c.x; Kf0[9]=c.y; Kf0[10]=c.z; Kf0[11]=c.w;
        Kf0[12]=d.x;Kf0[13]=d.y;Kf0[14]=d.z; Kf0[15]=d.w;
        kp = (const float4*)(Kh + ((size_t)c1 << 4));
        a = kp[0]; b = kp[1]; c = kp[2]; d = kp[3];
        Kf1[0]=a.x; Kf1[1]=a.y; Kf1[2]=a.z;  Kf1[3]=a.w;
        Kf1[4]=b.x; Kf1[5]=b.y; Kf1[6]=b.z;  Kf1[7]=b.w;
        Kf1[8]=c.x; Kf1[9]=c.y; Kf1[10]=c.z; Kf1[11]=c.w;
        Kf1[12]=d.x;Kf1[13]=d.y;Kf1[14]=d.z; Kf1[15]=d.w;
    }
    __syncthreads();               // Vf reads done before Ssc overwrites Vt

    const int cstart = (grp * 128) / 6;
    const int cend   = ((grp + 1) * 128) / 6;

    for (int chunk = cstart; chunk < cend; ++chunk) {
        const int qbase = chunk << 3;
        const int sb = chunk & 1;

        // ---- phase 1: scores (x 1/8) into Ssc ----
        #pragma unroll
        for (int r = 0; r < 8; ++r) {
            const float4* qp = (const float4*)(Qh + ((size_t)(qbase + r) << 4));
            float4 q0 = qp[0], q1 = qp[1], q2 = qp[2], q3 = qp[3];
            U.Ssc[r][c0] = dot16(q0, q1, q2, q3, Kf0) * 0.125f;
            U.Ssc[r][c1] = dot16(q0, q1, q2, q3, Kf1) * 0.125f;
        }
        __syncthreads();   // B1: scores visible

        // ---- wave w owns row w; contiguous b128 reads ----
        float s[16];
        #pragma unroll
        for (int b = 0; b < 4; ++b) {
            f32x4 v = *(const f32x4*)&U.Ssc[wave][(b << 8) + (lane << 2)];
            s[(b << 2) + 0] = v.x; s[(b << 2) + 1] = v.y;
            s[(b << 2) + 2] = v.z; s[(b << 2) + 3] = v.w;
        }
        __syncthreads();   // B2: Ssc consumed -> reusable as P

        // ---- phase 2: exact lower median (512th smallest) ----
        // Newton-seeded counting with exact bracket invariant:
        //   count(<= vL) = cl < 512 <= ch = count(<= vH)
        // Exits: cl==511 -> min{s>vL}; ch==512 -> max{s<=vH}; code collapse.
        float mn = 0.f;
        #pragma unroll
        for (int j = 0; j < 16; ++j) mn += s[j];
        #pragma unroll
        for (int off = 32; off > 0; off >>= 1) mn += __shfl_xor(mn, off);
        mn *= (1.0f / 1024.0f);
        float ad = 0.f;
        #pragma unroll
        for (int j = 0; j < 16; ++j) ad += fabsf(s[j] - mn);
        #pragma unroll
        for (int off = 32; off > 0; off >>= 1) ad += __shfl_xor(ad, off);
        // sigma ~= 1.2533*(ad/1024); step/count = sigma*2.5066/1024 = ad*pi/1024^2
        const float step = ad * (3.14159265f / (1024.0f * 1024.0f));

        unsigned int lo = 0x00800000u, hi = 0xFF7FFFFFu;
        int cl = 0, ch = 1024;
        float vL = -3.4e38f, vH = 3.4e38f;
        float t = mn, medf = 0.f;
        int found = 0;
        for (int pass = 0; pass < 64 && !found; ++pass) {
            int cnt = 0;
            #pragma unroll
            for (int j = 0; j < 16; ++j)
                cnt += __popcll(__ballot(s[j] <= t));
            const unsigned int tc = f2u(t);
            if (cnt >= 512) { hi = tc; ch = cnt; vH = t; }
            else            { lo = tc + 1; cl = cnt; vL = t; }
            if (cl == 511) {
                float c = 3.4e38f;
                #pragma unroll
                for (int j = 0; j < 16; ++j)
                    c = fminf(c, (s[j] > vL) ? s[j] : 3.4e38f);
                #pragma unroll
                for (int off = 32; off > 0; off >>= 1)
                    c = fminf(c, __shfl_xor(c, off));
                medf = c; found = 1;
            } else if (ch == 512) {
                float c = -3.4e38f;
                #pragma unroll
                for (int j = 0; j < 16; ++j)
                    c = fmaxf(c, (s[j] <= vH) ? s[j] : -3.4e38f);
                #pragma unroll
                for (int off = 32; off > 0; off >>= 1)
                    c = fmaxf(c, __shfl_xor(c, off));
                medf = c; found = 1;
            } else if (lo >= hi) {
                medf = u2f(lo); found = 1;   // heavy ties: code-exact
            } else {
                float tn = t + ((float)(512 - cnt) - 0.5f) * step;
                bool ok = (tn > vL) && (tn < vH);
                if (pass >= 5 && (pass & 1)) ok = false;   // periodic guarantee
                t = ok ? tn : u2f(lo + ((hi - lo) >> 1));
            }
        }
        if (!found) medf = u2f(lo);

        // ---- phase 2.5: masked exp (|s|<4: no max-shift), f16 round,
        //      row-sum of rounded values, vectorized P writes ----
        float sum = 0.f;
        #pragma unroll
        for (int b = 0; b < 4; ++b) {
            f16x4 hv;
            #pragma unroll
            for (int jj = 0; jj < 4; ++jj) {
                float e = (s[(b << 2) + jj] > medf) ? __expf(s[(b << 2) + jj]) : 0.f;
                _Float16 h = (_Float16)e;
                hv[jj] = h;
                sum += (float)h;
            }
            *(f16x4*)&U.P[wave][(b << 8) + (lane << 2)] = hv;
        }
        #pragma unroll
        for (int off = 32; off > 0; off >>= 1) sum += __shfl_xor(sum, off);
        if (lane == 0) sums[sb][wave] = sum;
        __syncthreads();   // B3: P + sums visible

        // ---- phase 3: PV via MFMA; A=P from LDS, B=V from registers ----
        f32x4 acc = {0.f, 0.f, 0.f, 0.f};
        const _Float16* Pr = &U.P[fm][fq << 3];
        #pragma unroll
        for (int kb = 0; kb < 4; ++kb) {
            f16x8 a = *(const f16x8*)(Pr + ((((wave << 2) + kb)) << 5));
            acc = __builtin_amdgcn_mfma_f32_16x16x32_f16(a, Vf[kb], acc, 0, 0, 0);
        }
        if (lane < 32) {   // C rows 0-7 live in quads 0-1
            #pragma unroll
            for (int i = 0; i < 4; ++i)
                part[(wave << 7) + (((fq << 2) + i) << 4) + fm] = acc[i];
        }
        __syncthreads();   // B4: partials visible (also: P reads done)

        // ---- reduce 8 partials + store; rotate active waves by chunk.
        // Safe without trailing barrier: next writes to part come after B3(c+1).
        const int rw = (wave - chunk) & 7;
        if (rw < 2) {
            const int t2 = (rw << 6) + lane;       // 0..127
            const int r = t2 >> 4, d = t2 & 15;
            float o = 0.f;
            #pragma unroll
            for (int w = 0; w < 8; ++w) o += part[(w << 7) + t2];
            const float inv = 1.0f / sums[sb][r];
            const int q = qbase + r;
            const int h = head >> 3, bp = head & 7;
            float* dst = Ob + (((size_t)(h >> 1)) << 18)
                            + ((size_t)(((h & 1) << 9) + (q >> 1)) << 8)
                            + ((q & 1) << 7) + (bp << 4) + d;
            *dst = o * inv;
        }
    }
}

// ---------------------------------------------------------------------------
extern "C" void kernel_launch(void* const* d_in, const int* in_sizes, int n_in,
                              void* d_out, int out_size, void* d_ws, size_t ws_size,
                              hipStream_t stream) {
    const float* x  = (const float*)d_in[0];
    const float* y  = (const float*)d_in[1];
    const float* Wq = (const float*)d_in[2];
    const float* bq = (const float*)d_in[3];
    const float* Wk = (const float*)d_in[4];
    const float* bk = (const float*)d_in[5];
    const float* Wv = (const float*)d_in[6];
    const float* bv = (const float*)d_in[7];
    const float* Wo = (const float*)d_in[8];
    const float* bo = (const float*)d_in[9];
    float* out = (float*)d_out;

    float* Q  = (float*)d_ws;
    float* K  = Q + 2097152;
    float* V  = K + 2097152;
    float* AO = V + 2097152;

    gemmQKV<<<dim3(128, 4, 3), dim3(256), 0, stream>>>(x, y, Wq, bq, Wk, bk,
                                                       Wv, bv, Q, K, V);
    attn<<<dim3(128, 6), dim3(512), 0, stream>>>(Q, K, V, AO);
    gemmOut<<<dim3(128, 4), dim3(256), 0, stream>>>(AO, Wo, bo, out);
}

// Round 7
// 345.211 us; speedup vs baseline: 1.5210x; 1.0812x over previous
//
#include <hip/hip_runtime.h>
#include <stdint.h>

// B=8, S=1024, D_MODEL=256, dk=dv=16, 128 pseudo-heads of 1024x16.
// ws layout (floats): Q[2M] | K[2M] | V[2M] | AO[2M] -> 32 MB.

typedef _Float16 f16x8 __attribute__((ext_vector_type(8)));
typedef _Float16 f16x4 __attribute__((ext_vector_type(4)));
typedef float    f32x4 __attribute__((ext_vector_type(4)));

// ---------------------------------------------------------------------------
// fp32 GEMM core: C[8192 x 256] = A @ W + bias. 64x64 tile, BK=32, 256 thr.
// ---------------------------------------------------------------------------
__device__ __forceinline__ void gemm_core(const float* __restrict__ A,
                                          const float* __restrict__ W,
                                          const float* __restrict__ bias,
                                          float* __restrict__ C)
{
    __shared__ float As[64][36];
    __shared__ float Bs[32][68];
    const int tid = threadIdx.x;
    const int tx = tid & 15, ty = tid >> 4;
    const int m0 = blockIdx.x << 6, n0 = blockIdx.y << 6;
    const int ar = tid >> 3, ac = (tid & 7) << 2;
    const int br = tid >> 4, bc = (tid & 15) << 2;

    float acc[4][4] = {};

    for (int k0 = 0; k0 < 256; k0 += 32) {
        float4 a0 = *(const float4*)(A + (size_t)(m0 + ar) * 256 + k0 + ac);
        float4 a1 = *(const float4*)(A + (size_t)(m0 + ar + 32) * 256 + k0 + ac);
        float4 b0 = *(const float4*)(W + (size_t)(k0 + br) * 256 + n0 + bc);
        float4 b1 = *(const float4*)(W + (size_t)(k0 + br + 16) * 256 + n0 + bc);
        *(float4*)&As[ar][ac]      = a0;
        *(float4*)&As[ar + 32][ac] = a1;
        *(float4*)&Bs[br][bc]      = b0;
        *(float4*)&Bs[br + 16][bc] = b1;
        __syncthreads();
        #pragma unroll
        for (int kk = 0; kk < 32; kk += 4) {
            float4 av[4], bv[4];
            #pragma unroll
            for (int i = 0; i < 4; ++i)
                av[i] = *(float4*)&As[ty + (i << 4)][kk];
            #pragma unroll
            for (int k2 = 0; k2 < 4; ++k2)
                bv[k2] = *(float4*)&Bs[kk + k2][tx << 2];
            #pragma unroll
            for (int i = 0; i < 4; ++i) {
                const float* ap = (const float*)&av[i];
                #pragma unroll
                for (int k2 = 0; k2 < 4; ++k2) {
                    const float* bp = (const float*)&bv[k2];
                    const float a = ap[k2];
                    acc[i][0] += a * bp[0];
                    acc[i][1] += a * bp[1];
                    acc[i][2] += a * bp[2];
                    acc[i][3] += a * bp[3];
                }
            }
        }
        __syncthreads();
    }

    float4 bb = *(const float4*)(bias + n0 + (tx << 2));
    #pragma unroll
    for (int i = 0; i < 4; ++i) {
        float4 o = make_float4(acc[i][0] + bb.x, acc[i][1] + bb.y,
                               acc[i][2] + bb.z, acc[i][3] + bb.w);
        *(float4*)(C + (size_t)(m0 + ty + (i << 4)) * 256 + n0 + (tx << 2)) = o;
    }
}

__global__ __launch_bounds__(256) void gemmQKV(
    const float* __restrict__ x, const float* __restrict__ y,
    const float* __restrict__ Wq, const float* __restrict__ bq,
    const float* __restrict__ Wk, const float* __restrict__ bk,
    const float* __restrict__ Wv, const float* __restrict__ bv,
    float* __restrict__ Q, float* __restrict__ K, float* __restrict__ V)
{
    const int z = blockIdx.z;
    const float* A = (z == 0) ? x  : y;
    const float* W = (z == 0) ? Wq : (z == 1) ? Wk : Wv;
    const float* b = (z == 0) ? bq : (z == 1) ? bk : bv;
    float*       C = (z == 0) ? Q  : (z == 1) ? K  : V;
    gemm_core(A, W, b, C);
}

__global__ __launch_bounds__(256) void gemmOut(
    const float* __restrict__ A, const float* __restrict__ W,
    const float* __restrict__ b, float* __restrict__ C)
{
    gemm_core(A, W, b, C);
}

// ---------------------------------------------------------------------------
// Attention
// ---------------------------------------------------------------------------
__device__ __forceinline__ float u2f(unsigned int m) {
    unsigned int x = (m & 0x80000000u) ? (m ^ 0x80000000u) : ~m;
    return __uint_as_float(x);
}
__device__ __forceinline__ unsigned int f2u(float f) {
    unsigned int x = __float_as_uint(f);
    return (x & 0x80000000u) ? ~x : (x | 0x80000000u);
}

// split float -> f16 hi/lo (hi+lo reproduces v to ~2^-22 relative)
__device__ __forceinline__ void split4(const float4& v, f16x4& h, f16x4& l) {
    h[0] = (_Float16)v.x; l[0] = (_Float16)(v.x - (float)h[0]);
    h[1] = (_Float16)v.y; l[1] = (_Float16)(v.y - (float)h[1]);
    h[2] = (_Float16)v.z; l[2] = (_Float16)(v.z - (float)h[2]);
    h[3] = (_Float16)v.w; l[3] = (_Float16)(v.w - (float)h[3]);
}

// grid (128 heads, 6 groups) = 768 blocks = 3/CU at waves_per_eu(6,6).
// Phase-1 QK^T is split-f16 MFMA: S = Ah*Bh + Al*Bh + Ah*Bl (dropped Al*Bl
// ~1e-6 rel — same regime as fp32 rounding). A and B share the (quad,j)->k
// packing so the k-permutation cancels; C mapping row=fq*4+reg, col=fm is the
// one verified by the passing PV MFMA. K scaled by 1/8 once at load.
// NOTE gfx950 naming: K=16 f16 MFMA is the LEGACY name ..._16x16x16f16
// (no underscore); only the 2xK gfx950 shapes use ..._16x16x32_f16.
__global__ __attribute__((amdgpu_waves_per_eu(6, 6)))
__launch_bounds__(512) void attn(
    const float* __restrict__ Qb, const float* __restrict__ Kb,
    const float* __restrict__ Vb, float* __restrict__ Ob)
{
    __shared__ union {
        float    Ssc[8][1028];     // pad 1028: MFMA C-writes land 32 distinct banks
        _Float16 P[16][1032];
        _Float16 Vt[16][1032];
    } U;
    __shared__ float part[1024];   // [8 waves][8 rows][16 d]
    __shared__ float sums[2][8];

    const int tid  = threadIdx.x;
    const int wave = tid >> 6, lane = tid & 63;
    const int head = blockIdx.x, grp = blockIdx.y;
    const float* Qh = Qb + ((size_t)head << 14);
    const float* Kh = Kb + ((size_t)head << 14);
    const float* Vh = Vb + ((size_t)head << 14);
    const int fm = lane & 15, fq = lane >> 4;

    // ---- stage V transposed (f16) into the union, grab register fragments ----
    for (int i = tid; i < 4096; i += 512) {
        float4 v = ((const float4*)Vh)[i];
        const int k = i >> 2, d0 = (i & 3) << 2;
        U.Vt[d0 + 0][k] = (_Float16)v.x;
        U.Vt[d0 + 1][k] = (_Float16)v.y;
        U.Vt[d0 + 2][k] = (_Float16)v.z;
        U.Vt[d0 + 3][k] = (_Float16)v.w;
    }
    __syncthreads();
    f16x8 Vf[4];
    #pragma unroll
    for (int kb = 0; kb < 4; ++kb)
        Vf[kb] = *(const f16x8*)&U.Vt[fm][(((wave << 2) + kb) << 5) + (fq << 3)];

    // ---- K fragments as f16 hi/lo (B operand), K pre-scaled by 1/8 ----
    // wave w owns k-cols [128w,128w+128): 8 tiles of 16. Lane holds
    // K[n0+fm][fq*4 .. fq*4+3].
    f16x4 Bh[8], Bl[8];
    #pragma unroll
    for (int kb = 0; kb < 8; ++kb) {
        const int krow = (wave << 7) + (kb << 4) + fm;
        float4 kv = *(const float4*)(Kh + ((size_t)krow << 4) + (fq << 2));
        kv.x *= 0.125f; kv.y *= 0.125f; kv.z *= 0.125f; kv.w *= 0.125f;
        split4(kv, Bh[kb], Bl[kb]);
    }
    __syncthreads();               // Vf reads done before Ssc overwrites Vt

    const int cstart = (grp * 128) / 6;
    const int cend   = ((grp + 1) * 128) / 6;

    for (int chunk = cstart; chunk < cend; ++chunk) {
        const int qbase = chunk << 3;
        const int sb = chunk & 1;

        // ---- phase 1: S = Q K^T/8 via split-f16 MFMA ----
        // A rows 8-15 duplicate rows 0-7 (harmless: C rows 8-15 unstored).
        f16x4 Ah, Al;
        {
            const int arow = qbase + (fm & 7);
            float4 qv = *(const float4*)(Qh + ((size_t)arow << 4) + (fq << 2));
            split4(qv, Ah, Al);
        }
        #pragma unroll
        for (int kb = 0; kb < 8; ++kb) {
            f32x4 c = {0.f, 0.f, 0.f, 0.f};
            c = __builtin_amdgcn_mfma_f32_16x16x16f16(Ah, Bh[kb], c, 0, 0, 0);
            c = __builtin_amdgcn_mfma_f32_16x16x16f16(Al, Bh[kb], c, 0, 0, 0);
            c = __builtin_amdgcn_mfma_f32_16x16x16f16(Ah, Bl[kb], c, 0, 0, 0);
            if (fq < 2) {
                const int col = (wave << 7) + (kb << 4) + fm;
                #pragma unroll
                for (int i = 0; i < 4; ++i)
                    U.Ssc[(fq << 2) + i][col] = c[i];
            }
        }
        __syncthreads();   // B1: scores visible

        // ---- wave w owns row w; contiguous b128 reads ----
        float s[16];
        #pragma unroll
        for (int b = 0; b < 4; ++b) {
            f32x4 v = *(const f32x4*)&U.Ssc[wave][(b << 8) + (lane << 2)];
            s[(b << 2) + 0] = v.x; s[(b << 2) + 1] = v.y;
            s[(b << 2) + 2] = v.z; s[(b << 2) + 3] = v.w;
        }
        __syncthreads();   // B2: Ssc consumed -> reusable as P

        // ---- phase 2: exact lower median (512th smallest) ----
        // Newton-seeded counting; bracket invariant keeps exactness:
        //   count(<= vL) = cl < 512 <= ch = count(<= vH)
        float mn = 0.f;
        #pragma unroll
        for (int j = 0; j < 16; ++j) mn += s[j];
        #pragma unroll
        for (int off = 32; off > 0; off >>= 1) mn += __shfl_xor(mn, off);
        mn *= (1.0f / 1024.0f);
        const float step = 0.0012239f;   // sigma~0.5 nominal: 0.5*2.5066/1024

        unsigned int lo = 0x00800000u, hi = 0xFF7FFFFFu;
        int cl = 0, ch = 1024;
        float vL = -3.4e38f, vH = 3.4e38f;
        float t = mn, medf = 0.f;
        int found = 0;
        for (int pass = 0; pass < 64 && !found; ++pass) {
            int cnt = 0;
            #pragma unroll
            for (int j = 0; j < 16; ++j)
                cnt += __popcll(__ballot(s[j] <= t));
            const unsigned int tc = f2u(t);
            if (cnt >= 512) { hi = tc; ch = cnt; vH = t; }
            else            { lo = tc + 1; cl = cnt; vL = t; }
            if (cl == 511) {
                float c = 3.4e38f;
                #pragma unroll
                for (int j = 0; j < 16; ++j)
                    c = fminf(c, (s[j] > vL) ? s[j] : 3.4e38f);
                #pragma unroll
                for (int off = 32; off > 0; off >>= 1)
                    c = fminf(c, __shfl_xor(c, off));
                medf = c; found = 1;
            } else if (ch == 512) {
                float c = -3.4e38f;
                #pragma unroll
                for (int j = 0; j < 16; ++j)
                    c = fmaxf(c, (s[j] <= vH) ? s[j] : -3.4e38f);
                #pragma unroll
                for (int off = 32; off > 0; off >>= 1)
                    c = fmaxf(c, __shfl_xor(c, off));
                medf = c; found = 1;
            } else if (lo >= hi) {
                medf = u2f(lo); found = 1;   // heavy ties: code-exact
            } else {
                float tn = t + ((float)(512 - cnt) - 0.5f) * step;
                bool ok = (tn > vL) && (tn < vH);
                if (pass >= 5 && (pass & 1)) ok = false;   // forced bisection
                t = ok ? tn : u2f(lo + ((hi - lo) >> 1));
            }
        }
        if (!found) medf = u2f(lo);

        // ---- phase 2.5: masked exp (|s|<4: no max-shift), f16 round,
        //      row-sum of rounded values, vectorized P writes ----
        float sum = 0.f;
        #pragma unroll
        for (int b = 0; b < 4; ++b) {
            f16x4 hv;
            #pragma unroll
            for (int jj = 0; jj < 4; ++jj) {
                float e = (s[(b << 2) + jj] > medf) ? __expf(s[(b << 2) + jj]) : 0.f;
                _Float16 h = (_Float16)e;
                hv[jj] = h;
                sum += (float)h;
            }
            *(f16x4*)&U.P[wave][(b << 8) + (lane << 2)] = hv;
        }
        #pragma unroll
        for (int off = 32; off > 0; off >>= 1) sum += __shfl_xor(sum, off);
        if (lane == 0) sums[sb][wave] = sum;
        __syncthreads();   // B3: P + sums visible

        // ---- phase 3: PV via MFMA; A=P from LDS, B=V from registers ----
        f32x4 acc = {0.f, 0.f, 0.f, 0.f};
        const _Float16* Pr = &U.P[fm][fq << 3];
        #pragma unroll
        for (int kb = 0; kb < 4; ++kb) {
            f16x8 a = *(const f16x8*)(Pr + ((((wave << 2) + kb)) << 5));
            acc = __builtin_amdgcn_mfma_f32_16x16x32_f16(a, Vf[kb], acc, 0, 0, 0);
        }
        if (lane < 32) {   // C rows 0-7 live in quads 0-1
            #pragma unroll
            for (int i = 0; i < 4; ++i)
                part[(wave << 7) + (((fq << 2) + i) << 4) + fm] = acc[i];
        }
        __syncthreads();   // B4: partials visible (also: P reads done)

        // ---- reduce 8 partials + store; rotate active waves by chunk ----
        const int rw = (wave - chunk) & 7;
        if (rw < 2) {
            const int t2 = (rw << 6) + lane;
            const int r = t2 >> 4, d = t2 & 15;
            float o = 0.f;
            #pragma unroll
            for (int w = 0; w < 8; ++w) o += part[(w << 7) + t2];
            const float inv = 1.0f / sums[sb][r];
            const int q = qbase + r;
            const int h = head >> 3, bp = head & 7;
            float* dst = Ob + (((size_t)(h >> 1)) << 18)
                            + ((size_t)(((h & 1) << 9) + (q >> 1)) << 8)
                            + ((q & 1) << 7) + (bp << 4) + d;
            *dst = o * inv;
        }
    }
}

// ---------------------------------------------------------------------------
extern "C" void kernel_launch(void* const* d_in, const int* in_sizes, int n_in,
                              void* d_out, int out_size, void* d_ws, size_t ws_size,
                              hipStream_t stream) {
    const float* x  = (const float*)d_in[0];
    const float* y  = (const float*)d_in[1];
    const float* Wq = (const float*)d_in[2];
    const float* bq = (const float*)d_in[3];
    const float* Wk = (const float*)d_in[4];
    const float* bk = (const float*)d_in[5];
    const float* Wv = (const float*)d_in[6];
    const float* bv = (const float*)d_in[7];
    const float* Wo = (const float*)d_in[8];
    const float* bo = (const float*)d_in[9];
    float* out = (float*)d_out;

    float* Q  = (float*)d_ws;
    float* K  = Q + 2097152;
    float* V  = K + 2097152;
    float* AO = V + 2097152;

    gemmQKV<<<dim3(128, 4, 3), dim3(256), 0, stream>>>(x, y, Wq, bq, Wk, bk,
                                                       Wv, bv, Q, K, V);
    attn<<<dim3(128, 6), dim3(512), 0, stream>>>(Q, K, V, AO);
    gemmOut<<<dim3(128, 4), dim3(256), 0, stream>>>(AO, Wo, bo, out);
}

// Round 8
// 329.683 us; speedup vs baseline: 1.5927x; 1.0471x over previous
//
#include <hip/hip_runtime.h>
#include <stdint.h>

// B=8, S=1024, D_MODEL=256, dk=dv=16, 128 pseudo-heads of 1024x16.
// ws layout (floats): Q[2M] | K[2M] | V[2M] | AO[2M] -> 32 MB.

typedef _Float16 f16x8 __attribute__((ext_vector_type(8)));
typedef _Float16 f16x4 __attribute__((ext_vector_type(4)));
typedef _Float16 f16x2 __attribute__((ext_vector_type(2)));
typedef float    f32x4 __attribute__((ext_vector_type(4)));

// ---------------------------------------------------------------------------
// Split-f16 MFMA GEMM: C[8192x256] = A[8192x256] @ W[256x256] + bias.
// C = Ah*Bh + Al*Bh + Ah*Bl (dropped Al*Bl ~2^-22 rel). Block 256 = 4 waves,
// tile 64(M) x 64(N), full K=256 staged once in LDS as hi/lo f16 transposed
// (Bt[n][k], pad 264) -> aligned b128 B-frag reads, ZERO barriers in K-loop.
// A-frags straight from global (each element read once per block).
// waves_per_eu(2,2): LDS 67.6KB forces 2 blocks/CU anyway; stop the allocator
// from spilling to chase higher occupancy (R1 lesson).
// ---------------------------------------------------------------------------
__device__ __forceinline__ void gemm_mfma(const float* __restrict__ A,
                                          const float* __restrict__ W,
                                          const float* __restrict__ bias,
                                          float* __restrict__ C)
{
    __shared__ _Float16 Bhi[64][264];
    __shared__ _Float16 Blo[64][264];
    const int tid = threadIdx.x;
    const int m0 = blockIdx.x << 6, n0 = blockIdx.y << 6;

    // ---- stage W[0:256][n0:n0+64] -> Bt hi/lo. Thread: k-pair (kk,kk+1),
    //      32 n's; f16x2 packed writes (k-adjacent) -> aligned b32.
    {
        const int kk = (tid & 127) << 1;       // even k
        const int nh = (tid >> 7) << 5;        // 0 or 32
        const float* w0 = W + (size_t)kk * 256 + n0 + nh;
        const float* w1 = w0 + 256;
        #pragma unroll
        for (int c4 = 0; c4 < 8; ++c4) {
            float4 v0 = *(const float4*)(w0 + (c4 << 2));
            float4 v1 = *(const float4*)(w1 + (c4 << 2));
            const float e0[4] = {v0.x, v0.y, v0.z, v0.w};
            const float e1[4] = {v1.x, v1.y, v1.z, v1.w};
            #pragma unroll
            for (int jj = 0; jj < 4; ++jj) {
                const int n = nh + (c4 << 2) + jj;
                _Float16 h0 = (_Float16)e0[jj];
                _Float16 h1 = (_Float16)e1[jj];
                f16x2 hp; hp[0] = h0; hp[1] = h1;
                f16x2 lp; lp[0] = (_Float16)(e0[jj] - (float)h0);
                          lp[1] = (_Float16)(e1[jj] - (float)h1);
                *(f16x2*)&Bhi[n][kk] = hp;
                *(f16x2*)&Blo[n][kk] = lp;
            }
        }
    }
    __syncthreads();

    const int wv = tid >> 6, lane = tid & 63;
    const int fm = lane & 15, fq = lane >> 4;
    const int arow = m0 + (wv << 4) + fm;

    f32x4 acc[4];
    #pragma unroll
    for (int cb = 0; cb < 4; ++cb) { acc[cb][0]=0.f; acc[cb][1]=0.f; acc[cb][2]=0.f; acc[cb][3]=0.f; }

    #pragma unroll
    for (int kb = 0; kb < 8; ++kb) {
        const float* ap = A + (size_t)arow * 256 + (kb << 5) + (fq << 3);
        float4 a0 = *(const float4*)ap;
        float4 a1 = *(const float4*)(ap + 4);
        const float ae[8] = {a0.x, a0.y, a0.z, a0.w, a1.x, a1.y, a1.z, a1.w};
        f16x8 Ah, Al;
        #pragma unroll
        for (int j = 0; j < 8; ++j) {
            _Float16 h = (_Float16)ae[j];
            Ah[j] = h;
            Al[j] = (_Float16)(ae[j] - (float)h);
        }
        #pragma unroll
        for (int cb = 0; cb < 4; ++cb) {
            f16x8 Bh = *(const f16x8*)&Bhi[(cb << 4) + fm][(kb << 5) + (fq << 3)];
            f16x8 Bl = *(const f16x8*)&Blo[(cb << 4) + fm][(kb << 5) + (fq << 3)];
            acc[cb] = __builtin_amdgcn_mfma_f32_16x16x32_f16(Ah, Bh, acc[cb], 0, 0, 0);
            acc[cb] = __builtin_amdgcn_mfma_f32_16x16x32_f16(Al, Bh, acc[cb], 0, 0, 0);
            acc[cb] = __builtin_amdgcn_mfma_f32_16x16x32_f16(Ah, Bl, acc[cb], 0, 0, 0);
        }
    }

    // epilogue: C row = m0+16w+4fq+i, col = n0+16cb+fm (verified C-mapping)
    #pragma unroll
    for (int cb = 0; cb < 4; ++cb) {
        const float bb = bias[n0 + (cb << 4) + fm];
        #pragma unroll
        for (int i = 0; i < 4; ++i)
            C[(size_t)(m0 + (wv << 4) + (fq << 2) + i) * 256
              + n0 + (cb << 4) + fm] = acc[cb][i] + bb;
    }
}

__global__ __attribute__((amdgpu_waves_per_eu(2, 2)))
__launch_bounds__(256) void gemmQKV(
    const float* __restrict__ x, const float* __restrict__ y,
    const float* __restrict__ Wq, const float* __restrict__ bq,
    const float* __restrict__ Wk, const float* __restrict__ bk,
    const float* __restrict__ Wv, const float* __restrict__ bv,
    float* __restrict__ Q, float* __restrict__ K, float* __restrict__ V)
{
    const int z = blockIdx.z;
    const float* A = (z == 0) ? x  : y;
    const float* W = (z == 0) ? Wq : (z == 1) ? Wk : Wv;
    const float* b = (z == 0) ? bq : (z == 1) ? bk : bv;
    float*       C = (z == 0) ? Q  : (z == 1) ? K  : V;
    gemm_mfma(A, W, b, C);
}

__global__ __attribute__((amdgpu_waves_per_eu(2, 2)))
__launch_bounds__(256) void gemmOut(
    const float* __restrict__ A, const float* __restrict__ W,
    const float* __restrict__ b, float* __restrict__ C)
{
    gemm_mfma(A, W, b, C);
}

// ---------------------------------------------------------------------------
// Attention (unchanged from R7)
// ---------------------------------------------------------------------------
__device__ __forceinline__ float u2f(unsigned int m) {
    unsigned int x = (m & 0x80000000u) ? (m ^ 0x80000000u) : ~m;
    return __uint_as_float(x);
}
__device__ __forceinline__ unsigned int f2u(float f) {
    unsigned int x = __float_as_uint(f);
    return (x & 0x80000000u) ? ~x : (x | 0x80000000u);
}

// split float -> f16 hi/lo (hi+lo reproduces v to ~2^-22 relative)
__device__ __forceinline__ void split4(const float4& v, f16x4& h, f16x4& l) {
    h[0] = (_Float16)v.x; l[0] = (_Float16)(v.x - (float)h[0]);
    h[1] = (_Float16)v.y; l[1] = (_Float16)(v.y - (float)h[1]);
    h[2] = (_Float16)v.z; l[2] = (_Float16)(v.z - (float)h[2]);
    h[3] = (_Float16)v.w; l[3] = (_Float16)(v.w - (float)h[3]);
}

__global__ __attribute__((amdgpu_waves_per_eu(6, 6)))
__launch_bounds__(512) void attn(
    const float* __restrict__ Qb, const float* __restrict__ Kb,
    const float* __restrict__ Vb, float* __restrict__ Ob)
{
    __shared__ union {
        float    Ssc[8][1028];     // pad 1028: MFMA C-writes land 32 distinct banks
        _Float16 P[16][1032];
        _Float16 Vt[16][1032];
    } U;
    __shared__ float part[1024];   // [8 waves][8 rows][16 d]
    __shared__ float sums[2][8];

    const int tid  = threadIdx.x;
    const int wave = tid >> 6, lane = tid & 63;
    const int head = blockIdx.x, grp = blockIdx.y;
    const float* Qh = Qb + ((size_t)head << 14);
    const float* Kh = Kb + ((size_t)head << 14);
    const float* Vh = Vb + ((size_t)head << 14);
    const int fm = lane & 15, fq = lane >> 4;

    // ---- stage V transposed (f16) into the union, grab register fragments ----
    for (int i = tid; i < 4096; i += 512) {
        float4 v = ((const float4*)Vh)[i];
        const int k = i >> 2, d0 = (i & 3) << 2;
        U.Vt[d0 + 0][k] = (_Float16)v.x;
        U.Vt[d0 + 1][k] = (_Float16)v.y;
        U.Vt[d0 + 2][k] = (_Float16)v.z;
        U.Vt[d0 + 3][k] = (_Float16)v.w;
    }
    __syncthreads();
    f16x8 Vf[4];
    #pragma unroll
    for (int kb = 0; kb < 4; ++kb)
        Vf[kb] = *(const f16x8*)&U.Vt[fm][(((wave << 2) + kb) << 5) + (fq << 3)];

    // ---- K fragments as f16 hi/lo (B operand), K pre-scaled by 1/8 ----
    f16x4 Bh[8], Bl[8];
    #pragma unroll
    for (int kb = 0; kb < 8; ++kb) {
        const int krow = (wave << 7) + (kb << 4) + fm;
        float4 kv = *(const float4*)(Kh + ((size_t)krow << 4) + (fq << 2));
        kv.x *= 0.125f; kv.y *= 0.125f; kv.z *= 0.125f; kv.w *= 0.125f;
        split4(kv, Bh[kb], Bl[kb]);
    }
    __syncthreads();               // Vf reads done before Ssc overwrites Vt

    const int cstart = (grp * 128) / 6;
    const int cend   = ((grp + 1) * 128) / 6;

    for (int chunk = cstart; chunk < cend; ++chunk) {
        const int qbase = chunk << 3;
        const int sb = chunk & 1;

        // ---- phase 1: S = Q K^T/8 via split-f16 MFMA ----
        f16x4 Ah, Al;
        {
            const int arow = qbase + (fm & 7);
            float4 qv = *(const float4*)(Qh + ((size_t)arow << 4) + (fq << 2));
            split4(qv, Ah, Al);
        }
        #pragma unroll
        for (int kb = 0; kb < 8; ++kb) {
            f32x4 c = {0.f, 0.f, 0.f, 0.f};
            c = __builtin_amdgcn_mfma_f32_16x16x16f16(Ah, Bh[kb], c, 0, 0, 0);
            c = __builtin_amdgcn_mfma_f32_16x16x16f16(Al, Bh[kb], c, 0, 0, 0);
            c = __builtin_amdgcn_mfma_f32_16x16x16f16(Ah, Bl[kb], c, 0, 0, 0);
            if (fq < 2) {
                const int col = (wave << 7) + (kb << 4) + fm;
                #pragma unroll
                for (int i = 0; i < 4; ++i)
                    U.Ssc[(fq << 2) + i][col] = c[i];
            }
        }
        __syncthreads();   // B1: scores visible

        // ---- wave w owns row w; contiguous b128 reads ----
        float s[16];
        #pragma unroll
        for (int b = 0; b < 4; ++b) {
            f32x4 v = *(const f32x4*)&U.Ssc[wave][(b << 8) + (lane << 2)];
            s[(b << 2) + 0] = v.x; s[(b << 2) + 1] = v.y;
            s[(b << 2) + 2] = v.z; s[(b << 2) + 3] = v.w;
        }
        __syncthreads();   // B2: Ssc consumed -> reusable as P

        // ---- phase 2: exact lower median (512th smallest) ----
        float mn = 0.f;
        #pragma unroll
        for (int j = 0; j < 16; ++j) mn += s[j];
        #pragma unroll
        for (int off = 32; off > 0; off >>= 1) mn += __shfl_xor(mn, off);
        mn *= (1.0f / 1024.0f);
        const float step = 0.0012239f;   // sigma~0.5 nominal: 0.5*2.5066/1024

        unsigned int lo = 0x00800000u, hi = 0xFF7FFFFFu;
        int cl = 0, ch = 1024;
        float vL = -3.4e38f, vH = 3.4e38f;
        float t = mn, medf = 0.f;
        int found = 0;
        for (int pass = 0; pass < 64 && !found; ++pass) {
            int cnt = 0;
            #pragma unroll
            for (int j = 0; j < 16; ++j)
                cnt += __popcll(__ballot(s[j] <= t));
            const unsigned int tc = f2u(t);
            if (cnt >= 512) { hi = tc; ch = cnt; vH = t; }
            else            { lo = tc + 1; cl = cnt; vL = t; }
            if (cl == 511) {
                float c = 3.4e38f;
                #pragma unroll
                for (int j = 0; j < 16; ++j)
                    c = fminf(c, (s[j] > vL) ? s[j] : 3.4e38f);
                #pragma unroll
                for (int off = 32; off > 0; off >>= 1)
                    c = fminf(c, __shfl_xor(c, off));
                medf = c; found = 1;
            } else if (ch == 512) {
                float c = -3.4e38f;
                #pragma unroll
                for (int j = 0; j < 16; ++j)
                    c = fmaxf(c, (s[j] <= vH) ? s[j] : -3.4e38f);
                #pragma unroll
                for (int off = 32; off > 0; off >>= 1)
                    c = fmaxf(c, __shfl_xor(c, off));
                medf = c; found = 1;
            } else if (lo >= hi) {
                medf = u2f(lo); found = 1;   // heavy ties: code-exact
            } else {
                float tn = t + ((float)(512 - cnt) - 0.5f) * step;
                bool ok = (tn > vL) && (tn < vH);
                if (pass >= 5 && (pass & 1)) ok = false;   // forced bisection
                t = ok ? tn : u2f(lo + ((hi - lo) >> 1));
            }
        }
        if (!found) medf = u2f(lo);

        // ---- phase 2.5: masked exp, f16 round, row-sum, P writes ----
        float sum = 0.f;
        #pragma unroll
        for (int b = 0; b < 4; ++b) {
            f16x4 hv;
            #pragma unroll
            for (int jj = 0; jj < 4; ++jj) {
                float e = (s[(b << 2) + jj] > medf) ? __expf(s[(b << 2) + jj]) : 0.f;
                _Float16 h = (_Float16)e;
                hv[jj] = h;
                sum += (float)h;
            }
            *(f16x4*)&U.P[wave][(b << 8) + (lane << 2)] = hv;
        }
        #pragma unroll
        for (int off = 32; off > 0; off >>= 1) sum += __shfl_xor(sum, off);
        if (lane == 0) sums[sb][wave] = sum;
        __syncthreads();   // B3: P + sums visible

        // ---- phase 3: PV via MFMA; A=P from LDS, B=V from registers ----
        f32x4 acc = {0.f, 0.f, 0.f, 0.f};
        const _Float16* Pr = &U.P[fm][fq << 3];
        #pragma unroll
        for (int kb = 0; kb < 4; ++kb) {
            f16x8 a = *(const f16x8*)(Pr + ((((wave << 2) + kb)) << 5));
            acc = __builtin_amdgcn_mfma_f32_16x16x32_f16(a, Vf[kb], acc, 0, 0, 0);
        }
        if (lane < 32) {   // C rows 0-7 live in quads 0-1
            #pragma unroll
            for (int i = 0; i < 4; ++i)
                part[(wave << 7) + (((fq << 2) + i) << 4) + fm] = acc[i];
        }
        __syncthreads();   // B4: partials visible (also: P reads done)

        // ---- reduce 8 partials + store; rotate active waves by chunk ----
        const int rw = (wave - chunk) & 7;
        if (rw < 2) {
            const int t2 = (rw << 6) + lane;
            const int r = t2 >> 4, d = t2 & 15;
            float o = 0.f;
            #pragma unroll
            for (int w = 0; w < 8; ++w) o += part[(w << 7) + t2];
            const float inv = 1.0f / sums[sb][r];
            const int q = qbase + r;
            const int h = head >> 3, bp = head & 7;
            float* dst = Ob + (((size_t)(h >> 1)) << 18)
                            + ((size_t)(((h & 1) << 9) + (q >> 1)) << 8)
                            + ((q & 1) << 7) + (bp << 4) + d;
            *dst = o * inv;
        }
    }
}

// ---------------------------------------------------------------------------
extern "C" void kernel_launch(void* const* d_in, const int* in_sizes, int n_in,
                              void* d_out, int out_size, void* d_ws, size_t ws_size,
                              hipStream_t stream) {
    const float* x  = (const float*)d_in[0];
    const float* y  = (const float*)d_in[1];
    const float* Wq = (const float*)d_in[2];
    const float* bq = (const float*)d_in[3];
    const float* Wk = (const float*)d_in[4];
    const float* bk = (const float*)d_in[5];
    const float* Wv = (const float*)d_in[6];
    const float* bv = (const float*)d_in[7];
    const float* Wo = (const float*)d_in[8];
    const float* bo = (const float*)d_in[9];
    float* out = (float*)d_out;

    float* Q  = (float*)d_ws;
    float* K  = Q + 2097152;
    float* V  = K + 2097152;
    float* AO = V + 2097152;

    gemmQKV<<<dim3(128, 4, 3), dim3(256), 0, stream>>>(x, y, Wq, bq, Wk, bk,
                                                       Wv, bv, Q, K, V);
    attn<<<dim3(128, 6), dim3(512), 0, stream>>>(Q, K, V, AO);
    gemmOut<<<dim3(128, 4), dim3(256), 0, stream>>>(AO, Wo, bo, out);
}